// Round 16
// baseline (169.258 us; speedup 1.0000x reference)
//
#include <hip/hip_runtime.h>
#include <math.h>

#define N_NODES 8192
#define FDIM 256
#define DDIM 128
#define SLOPE 0.2f
#define ELLW 128      // slots/row incl. dups; true max ~56, validated R5-R15
#define NR 64         // rows owned per scan block
#define NSCAN (N_NODES / NR)   // 128 scan blocks

typedef __attribute__((ext_vector_type(8))) short bf16x8;
typedef __attribute__((ext_vector_type(4))) float f32x4;

__device__ __forceinline__ unsigned short f2bf(float f) {     // RNE fp32->bf16
    unsigned u = __float_as_uint(f);
    u += 0x7fffu + ((u >> 16) & 1u);
    return (unsigned short)(u >> 16);
}
__device__ __forceinline__ float bf2f(unsigned short h) {
    return __uint_as_float(((unsigned)h) << 16);
}

// ---------------- prep: pack Ws into MFMA B-fragment order (hi/lo bf16) -------------
// Bp layout: frag (ct,ks) -> 64 lanes x 8 elems; lane l, elem e holds
// Ws[ks*32+(l>>4)*8+e][ct*16+(l&15)]. A wave's B load = 1KB contiguous.
__global__ __launch_bounds__(256) void prep_k(const float* __restrict__ Ws,
                                              unsigned short* __restrict__ Bphi,
                                              unsigned short* __restrict__ Bplo) {
    int tid = blockIdx.x * 256 + threadIdx.x;    // 16 blocks -> tid < 4096
    int ct = tid >> 9, ks = (tid >> 6) & 7, l = tid & 63;
    int kbase = ks * 32 + (l >> 4) * 8;
    int col = ct * 16 + (l & 15);
    bf16x8 h, lo;
#pragma unroll
    for (int e = 0; e < 8; e++) {
        float v = Ws[(size_t)(kbase + e) * DDIM + col];
        unsigned short hq = f2bf(v);
        h[e] = (short)hq;
        lo[e] = (short)f2bf(v - bf2f(hq));
    }
    *(bf16x8*)(Bphi + (size_t)tid * 8) = h;
    *(bf16x8*)(Bplo + (size_t)tid * 8) = lo;
}

// ---------------- mega: gemm role (bid<512) + edge-scan role (bid>=512) -------------
// gemm: 16 rows x 128 cols, A staged fp32->hi/lo bf16 in LDS (17KB), B from packed
// global (coalesced 1KB wave loads, L2-hot). 48 MFMA/wave, ONE barrier.
// scan: block owns 64 rows; scans all E row-indices (int4, L2-broadcast); slots via
// LDS atomics; plain stores for cnt. ZERO global atomics (R15's 19us was the
// device-scope atomicAdd pipe).
__global__ __launch_bounds__(256) void mega_k(const int* __restrict__ edge, int E,
                                              const float* __restrict__ X,
                                              const unsigned short* __restrict__ Bphi,
                                              const unsigned short* __restrict__ Bplo,
                                              const float* __restrict__ a,
                                              unsigned short* __restrict__ WhB,
                                              float* __restrict__ s1,
                                              float* __restrict__ s2,
                                              unsigned* __restrict__ cnt,
                                              unsigned* __restrict__ ell) {
    __shared__ unsigned short Ah[16 * 264], Al[16 * 264];   // 16.5 KB
    __shared__ float ps1[64], ps2[64];
    __shared__ unsigned lcnt[NR];
    int bid = blockIdx.x, t = threadIdx.x;

    if (bid >= 512) {                    // ---- scan role: 128 blocks, 64 rows each ----
        int base = (bid - 512) * NR;
        if (t < NR) lcnt[t] = 0u;
        __syncthreads();
        const int4* r4p = (const int4*)edge;
        int nv4 = E >> 2;
        for (int idx4 = t; idx4 < nv4; idx4 += 256) {
            int4 r4 = r4p[idx4];
            int e0 = idx4 * 4;
#pragma unroll
            for (int j = 0; j < 4; j++) {
                int r = (&r4.x)[j];
                if ((unsigned)(r - base) < NR) {
                    int c = edge[E + e0 + j];
                    unsigned slot = atomicAdd(&lcnt[r - base], 1u);
                    if (slot < ELLW) ell[(size_t)r * ELLW + slot] = (unsigned)c;
                }
            }
        }
        __syncthreads();
        if (t < NR) cnt[base + t] = lcnt[t];
        return;
    }

    // ---- gemm role: 512 blocks ----
    int w = t >> 6, lane = t & 63, lr = lane & 15, kg = lane >> 4;
    int row0 = bid * 16;

    const float4* Xg = (const float4*)(X + (size_t)row0 * FDIM);
#pragma unroll
    for (int i = 0; i < 4; i++) {
        int lin = t + 256 * i;
        int r = lin >> 6, q = lin & 63;
        float4 v = Xg[r * 64 + q];
        ushort4 h, l;
        h.x = f2bf(v.x); l.x = f2bf(v.x - bf2f(h.x));
        h.y = f2bf(v.y); l.y = f2bf(v.y - bf2f(h.y));
        h.z = f2bf(v.z); l.z = f2bf(v.z - bf2f(h.z));
        h.w = f2bf(v.w); l.w = f2bf(v.w - bf2f(h.w));
        *(ushort4*)(Ah + r * 264 + q * 4) = h;
        *(ushort4*)(Al + r * 264 + q * 4) = l;
    }
    __syncthreads();                     // the only staging barrier

    f32x4 acc0 = (f32x4){0.f, 0.f, 0.f, 0.f};
    f32x4 acc1 = (f32x4){0.f, 0.f, 0.f, 0.f};
    int ct0 = 2 * w, ct1 = 2 * w + 1;

#pragma unroll 2
    for (int ks = 0; ks < 8; ks++) {
        bf16x8 ahi = *(bf16x8*)(Ah + lr * 264 + ks * 32 + kg * 8);
        bf16x8 alo = *(bf16x8*)(Al + lr * 264 + ks * 32 + kg * 8);
        size_t o0 = (size_t)((ct0 * 8 + ks) * 64 + lane) * 8;
        size_t o1 = (size_t)((ct1 * 8 + ks) * 64 + lane) * 8;
        bf16x8 bh0 = *(const bf16x8*)(Bphi + o0);
        bf16x8 bl0 = *(const bf16x8*)(Bplo + o0);
        bf16x8 bh1 = *(const bf16x8*)(Bphi + o1);
        bf16x8 bl1 = *(const bf16x8*)(Bplo + o1);
        acc0 = __builtin_amdgcn_mfma_f32_16x16x32_bf16(ahi, bh0, acc0, 0, 0, 0);
        acc0 = __builtin_amdgcn_mfma_f32_16x16x32_bf16(ahi, bl0, acc0, 0, 0, 0);
        acc0 = __builtin_amdgcn_mfma_f32_16x16x32_bf16(alo, bh0, acc0, 0, 0, 0);
        acc1 = __builtin_amdgcn_mfma_f32_16x16x32_bf16(ahi, bh1, acc1, 0, 0, 0);
        acc1 = __builtin_amdgcn_mfma_f32_16x16x32_bf16(ahi, bl1, acc1, 0, 0, 0);
        acc1 = __builtin_amdgcn_mfma_f32_16x16x32_bf16(alo, bh1, acc1, 0, 0, 0);
    }

    // epilogue: bf16 WhB + deterministic s1/s2 (fixed-order LDS reduce)
#pragma unroll
    for (int r = 0; r < 4; r++) {
        int row = row0 + kg * 4 + r;            // D: row=(lane>>4)*4+reg [m89-verified]
        int c0 = ct0 * 16 + lr, c1 = ct1 * 16 + lr;
        float v0 = acc0[r], v1 = acc1[r];
        WhB[(size_t)row * DDIM + c0] = f2bf(v0);
        WhB[(size_t)row * DDIM + c1] = f2bf(v1);
        float q1 = v0 * a[c0] + v1 * a[c1];
        float q2 = v0 * a[DDIM + c0] + v1 * a[DDIM + c1];
        for (int o = 1; o < 16; o <<= 1) {
            q1 += __shfl_xor(q1, o, 16);
            q2 += __shfl_xor(q2, o, 16);
        }
        if (lr == 0) { ps1[w * 16 + kg * 4 + r] = q1; ps2[w * 16 + kg * 4 + r] = q2; }
    }
    __syncthreads();
    if (t < 16) {
        s1[row0 + t] = (ps1[t] + ps1[16 + t]) + (ps1[32 + t] + ps1[48 + t]);
        s2[row0 + t] = (ps2[t] + ps2[16 + t]) + (ps2[32 + t] + ps2[48 + t]);
    }
}

// ---------------- wave-per-row: dedup + softmax + bf16 gather + elu (R12-R15) -------
__global__ __launch_bounds__(256) void row_wave_k(const unsigned* __restrict__ cnt,
                                                  const unsigned* __restrict__ ell,
                                                  const float* __restrict__ s1v,
                                                  const float* __restrict__ s2v,
                                                  const unsigned short* __restrict__ WhB,
                                                  float* __restrict__ out) {
    __shared__ unsigned bmw[4][256];
    __shared__ float    pl[4][ELLW];
    __shared__ unsigned jl[4][ELLW];

    int w = threadIdx.x >> 6, lane = threadIdx.x & 63;
    int i = blockIdx.x * 4 + w;
    const ushort2* WhB2 = (const ushort2*)WhB;

    ((uint4*)bmw[w])[lane] = make_uint4(0u, 0u, 0u, 0u);
    unsigned deg = cnt[i];
    if (deg > ELLW) deg = ELLW;
    __syncthreads();

    if (deg == 0u) {
        float sx = 0.f, sy = 0.f;
        for (int rr = 0; rr < N_NODES; rr++) {
            ushort2 u = WhB2[(size_t)rr * 64 + lane];
            sx += bf2f(u.x); sy += bf2f(u.y);
        }
        sx *= (1.0f / N_NODES); sy *= (1.0f / N_NODES);
        sx = sx > 0.f ? sx : __expf(sx) - 1.f;
        sy = sy > 0.f ? sy : __expf(sy) - 1.f;
        ((float2*)out)[(size_t)i * 64 + lane] = make_float2(sx, sy);
        return;
    }

    const unsigned* erow = ell + (size_t)i * ELLW;
    unsigned j0 = 0u, j1 = 0u;
    bool v0 = false, v1 = false;
    if (lane < (int)deg) j0 = erow[lane];
    if (lane + 64 < (int)deg) j1 = erow[lane + 64];
    if (lane < (int)deg) {
        unsigned m = 1u << (j0 & 31);
        v0 = !(atomicOr(&bmw[w][j0 >> 5], m) & m);
    }
    if (lane + 64 < (int)deg) {
        unsigned m = 1u << (j1 & 31);
        v1 = !(atomicOr(&bmw[w][j1 >> 5], m) & m);
    }

    float s1 = s1v[i];
    float e0 = -3e38f, e1 = -3e38f;
    if (v0) { float e = s1 + s2v[j0]; e0 = e > 0.f ? e : SLOPE * e; }
    if (v1) { float e = s1 + s2v[j1]; e1 = e > 0.f ? e : SLOPE * e; }

    float mx = fmaxf(e0, e1);
    for (int o = 32; o; o >>= 1) mx = fmaxf(mx, __shfl_xor(mx, o, 64));

    float p0 = v0 ? __expf(e0 - mx) : 0.f;
    float p1 = v1 ? __expf(e1 - mx) : 0.f;
    float s = p0 + p1;
    for (int o = 32; o; o >>= 1) s += __shfl_xor(s, o, 64);
    float inv = 1.0f / s;

    pl[w][lane] = p0;      jl[w][lane] = j0;
    pl[w][lane + 64] = p1; jl[w][lane + 64] = j1;

    float ax = 0.f, ay = 0.f;
#pragma unroll 8
    for (unsigned n = 0; n < deg; ++n) {
        float p = pl[w][n];
        unsigned j = jl[w][n];
        ushort2 u = WhB2[(size_t)j * 64 + lane];
        ax = fmaf(p, bf2f(u.x), ax);
        ay = fmaf(p, bf2f(u.y), ay);
    }
    ax *= inv; ay *= inv;
    ax = ax > 0.f ? ax : __expf(ax) - 1.f;
    ay = ay > 0.f ? ay : __expf(ay) - 1.f;
    ((float2*)out)[(size_t)i * 64 + lane] = make_float2(ax, ay);
}

extern "C" void kernel_launch(void* const* d_in, const int* in_sizes, int n_in,
                              void* d_out, int out_size, void* d_ws, size_t ws_size,
                              hipStream_t stream) {
    const int*   edge = (const int*)d_in[0];    // [2, E] int32
    const float* X    = (const float*)d_in[1];  // [N, F]
    const float* Ws   = (const float*)d_in[2];  // [F, D]
    const float* a    = (const float*)d_in[3];  // [2D, 1]
    float*       out  = (float*)d_out;          // [N, D]
    int E = in_sizes[0] / 2;

    char* ws = (char*)d_ws;
    size_t off = 0;
    unsigned*       cnt  = (unsigned*)(ws + off); off += N_NODES * 4;                 // 32 KB
    unsigned*       ell  = (unsigned*)(ws + off); off += (size_t)N_NODES * ELLW * 4;  // 4 MB
    float*          s1   = (float*)(ws + off);    off += N_NODES * 4;                 // 32 KB
    float*          s2   = (float*)(ws + off);    off += N_NODES * 4;                 // 32 KB
    unsigned short* WhB  = (unsigned short*)(ws + off); off += (size_t)N_NODES * DDIM * 2; // 2 MB
    unsigned short* Bphi = (unsigned short*)(ws + off); off += (size_t)FDIM * DDIM * 2;    // 64 KB
    unsigned short* Bplo = (unsigned short*)(ws + off); off += (size_t)FDIM * DDIM * 2;    // 64 KB

    prep_k<<<16, 256, 0, stream>>>(Ws, Bphi, Bplo);
    mega_k<<<512 + NSCAN, 256, 0, stream>>>(edge, E, X, Bphi, Bplo, a, WhB, s1, s2, cnt, ell);
    row_wave_k<<<N_NODES / 4, 256, 0, stream>>>(cnt, ell, s1, s2, WhB, out);
}

// Round 17
// 40.505 us; speedup vs baseline: 4.1787x; 4.1787x over previous
//
#include <hip/hip_runtime.h>
#include <math.h>

#define N_NODES 8192
#define FDIM 256
#define DDIM 128
#define SLOPE 0.2f
#define WPR 256       // bitmap words per row (8192 bits)
#define MAXD 128      // max unique neighbors kept; true max ~56, validated R5-R16

typedef __attribute__((ext_vector_type(8))) short bf16x8;
typedef __attribute__((ext_vector_type(4))) float f32x4;

__device__ __forceinline__ unsigned short f2bf(float f) {     // RNE fp32->bf16
    unsigned u = __float_as_uint(f);
    u += 0x7fffu + ((u >> 16) & 1u);
    return (unsigned short)(u >> 16);
}
__device__ __forceinline__ float bf2f(unsigned short h) {
    return __uint_as_float(((unsigned)h) << 16);
}

// ---------------- prep: zero 8MB bitmap + pack Ws into MFMA B-fragment order --------
// 256 blocks. Bitmap: 524288 uint4 / 65536 threads = 8 each. Blocks 0-15 also pack B.
__global__ __launch_bounds__(256) void prep_k(const float* __restrict__ Ws,
                                              unsigned short* __restrict__ Bphi,
                                              unsigned short* __restrict__ Bplo,
                                              unsigned* __restrict__ bm) {
    int b = blockIdx.x, t = threadIdx.x;
    size_t zi = (size_t)b * 256 + t;
    uint4 z = make_uint4(0u, 0u, 0u, 0u);
#pragma unroll
    for (int k = 0; k < 8; k++) ((uint4*)bm)[(size_t)k * 65536 + zi] = z;

    if (b >= 16) return;
    int tid = b * 256 + t;                       // < 4096
    int ct = tid >> 9, ks = (tid >> 6) & 7, l = tid & 63;
    int kbase = ks * 32 + (l >> 4) * 8;
    int col = ct * 16 + (l & 15);
    bf16x8 h, lo;
#pragma unroll
    for (int e = 0; e < 8; e++) {
        float v = Ws[(size_t)(kbase + e) * DDIM + col];
        unsigned short hq = f2bf(v);
        h[e] = (short)hq;
        lo[e] = (short)f2bf(v - bf2f(hq));
    }
    *(bf16x8*)(Bphi + (size_t)tid * 8) = h;
    *(bf16x8*)(Bplo + (size_t)tid * 8) = lo;
}

// ---------------- mega: gemm role (bid<512) + bitmap-build role (bid>=512) ----------
// build: one edge per thread, fire-and-forget atomicOr (no return value -> no
// round-trip dependency; R15's 17-19us was atomicAdd-with-return latency).
// gemm: 16 rows x 128 cols, A fp32->hi/lo bf16 in LDS (17KB), B packed-global.
__global__ __launch_bounds__(256) void mega_k(const int* __restrict__ edge, int E,
                                              const float* __restrict__ X,
                                              const unsigned short* __restrict__ Bphi,
                                              const unsigned short* __restrict__ Bplo,
                                              const float* __restrict__ a,
                                              unsigned short* __restrict__ WhB,
                                              float* __restrict__ s1,
                                              float* __restrict__ s2,
                                              unsigned* __restrict__ bm) {
    __shared__ unsigned short Ah[16 * 264], Al[16 * 264];   // 16.5 KB
    __shared__ float ps1[64], ps2[64];
    int bid = blockIdx.x, t = threadIdx.x;

    if (bid >= 512) {                    // ---- build role ----
        int e = (bid - 512) * 256 + t;
        if (e < E) {
            int r = edge[e];             // edge_index[0][e] : softmax row
            int c = edge[E + e];         // edge_index[1][e] : neighbor
            atomicOr(&bm[(size_t)r * WPR + (c >> 5)], 1u << (c & 31));
        }
        return;
    }

    // ---- gemm role: 512 blocks (R16 math, hardware-validated fragments) ----
    int w = t >> 6, lane = t & 63, lr = lane & 15, kg = lane >> 4;
    int row0 = bid * 16;

    const float4* Xg = (const float4*)(X + (size_t)row0 * FDIM);
#pragma unroll
    for (int i = 0; i < 4; i++) {
        int lin = t + 256 * i;
        int r = lin >> 6, q = lin & 63;
        float4 v = Xg[r * 64 + q];
        ushort4 h, l;
        h.x = f2bf(v.x); l.x = f2bf(v.x - bf2f(h.x));
        h.y = f2bf(v.y); l.y = f2bf(v.y - bf2f(h.y));
        h.z = f2bf(v.z); l.z = f2bf(v.z - bf2f(h.z));
        h.w = f2bf(v.w); l.w = f2bf(v.w - bf2f(h.w));
        *(ushort4*)(Ah + r * 264 + q * 4) = h;
        *(ushort4*)(Al + r * 264 + q * 4) = l;
    }
    __syncthreads();

    f32x4 acc0 = (f32x4){0.f, 0.f, 0.f, 0.f};
    f32x4 acc1 = (f32x4){0.f, 0.f, 0.f, 0.f};
    int ct0 = 2 * w, ct1 = 2 * w + 1;

#pragma unroll 2
    for (int ks = 0; ks < 8; ks++) {
        bf16x8 ahi = *(bf16x8*)(Ah + lr * 264 + ks * 32 + kg * 8);
        bf16x8 alo = *(bf16x8*)(Al + lr * 264 + ks * 32 + kg * 8);
        size_t o0 = (size_t)((ct0 * 8 + ks) * 64 + lane) * 8;
        size_t o1 = (size_t)((ct1 * 8 + ks) * 64 + lane) * 8;
        bf16x8 bh0 = *(const bf16x8*)(Bphi + o0);
        bf16x8 bl0 = *(const bf16x8*)(Bplo + o0);
        bf16x8 bh1 = *(const bf16x8*)(Bphi + o1);
        bf16x8 bl1 = *(const bf16x8*)(Bplo + o1);
        acc0 = __builtin_amdgcn_mfma_f32_16x16x32_bf16(ahi, bh0, acc0, 0, 0, 0);
        acc0 = __builtin_amdgcn_mfma_f32_16x16x32_bf16(ahi, bl0, acc0, 0, 0, 0);
        acc0 = __builtin_amdgcn_mfma_f32_16x16x32_bf16(alo, bh0, acc0, 0, 0, 0);
        acc1 = __builtin_amdgcn_mfma_f32_16x16x32_bf16(ahi, bh1, acc1, 0, 0, 0);
        acc1 = __builtin_amdgcn_mfma_f32_16x16x32_bf16(ahi, bl1, acc1, 0, 0, 0);
        acc1 = __builtin_amdgcn_mfma_f32_16x16x32_bf16(alo, bh1, acc1, 0, 0, 0);
    }

#pragma unroll
    for (int r = 0; r < 4; r++) {
        int row = row0 + kg * 4 + r;            // D: row=(lane>>4)*4+reg [m89-verified]
        int c0 = ct0 * 16 + lr, c1 = ct1 * 16 + lr;
        float v0 = acc0[r], v1 = acc1[r];
        WhB[(size_t)row * DDIM + c0] = f2bf(v0);
        WhB[(size_t)row * DDIM + c1] = f2bf(v1);
        float q1 = v0 * a[c0] + v1 * a[c1];
        float q2 = v0 * a[DDIM + c0] + v1 * a[DDIM + c1];
        for (int o = 1; o < 16; o <<= 1) {
            q1 += __shfl_xor(q1, o, 16);
            q2 += __shfl_xor(q2, o, 16);
        }
        if (lr == 0) { ps1[w * 16 + kg * 4 + r] = q1; ps2[w * 16 + kg * 4 + r] = q2; }
    }
    __syncthreads();
    if (t < 16) {
        s1[row0 + t] = (ps1[t] + ps1[16 + t]) + (ps1[32 + t] + ps1[48 + t]);
        s2[row0 + t] = (ps2[t] + ps2[16 + t]) + (ps2[32 + t] + ps2[48 + t]);
    }
}

// ---------------- wave-per-row from bitmap: extract + softmax + bf16 gather + elu ---
// Wave reads its row's 1KB bitmap (uint4/lane, coalesced), extracts set bits (dedup
// is free), appends (j, leaky-score) to wave-private LDS, then softmax + gather as
// the validated R12-R15 kernel. No ELL, no cnt, no dedup phase.
__global__ __launch_bounds__(256) void row_bm_k(const unsigned* __restrict__ bm,
                                                const float* __restrict__ s1v,
                                                const float* __restrict__ s2v,
                                                const unsigned short* __restrict__ WhB,
                                                float* __restrict__ out) {
    __shared__ float    pe[4][MAXD];
    __shared__ unsigned jl[4][MAXD];
    __shared__ unsigned lcnt[4];

    int w = threadIdx.x >> 6, lane = threadIdx.x & 63;
    int i = blockIdx.x * 4 + w;
    const ushort2* WhB2 = (const ushort2*)WhB;

    if (lane == 0) lcnt[w] = 0u;         // wave-private; in-order DS unit makes this
                                         // visible to the wave's later atomics
    float s1i = s1v[i];
    uint4 wd = ((const uint4*)(bm + (size_t)i * WPR))[lane];   // words 4l..4l+3

    float lmax = -3e38f;
#pragma unroll
    for (int q = 0; q < 4; q++) {
        unsigned x = (&wd.x)[q];
        int base = (lane * 4 + q) * 32;
        while (x) {
            int bpos = __ffs(x) - 1; x &= x - 1;
            unsigned j = (unsigned)(base + bpos);
            float e = s1i + s2v[j];
            e = e > 0.f ? e : SLOPE * e;
            lmax = fmaxf(lmax, e);
            unsigned pos = atomicAdd(&lcnt[w], 1u);
            if (pos < MAXD) { jl[w][pos] = j; pe[w][pos] = e; }
        }
    }
    for (int o = 32; o; o >>= 1) lmax = fmaxf(lmax, __shfl_xor(lmax, o, 64));
    unsigned deg = lcnt[w];              // all wave DS ops precede this read
    if (deg > MAXD) deg = MAXD;

    if (deg == 0u) {
        // all-masked row -> uniform softmax -> elu(mean(Wh)); never taken on this input
        float sx = 0.f, sy = 0.f;
        for (int rr = 0; rr < N_NODES; rr++) {
            ushort2 u = WhB2[(size_t)rr * 64 + lane];
            sx += bf2f(u.x); sy += bf2f(u.y);
        }
        sx *= (1.0f / N_NODES); sy *= (1.0f / N_NODES);
        sx = sx > 0.f ? sx : __expf(sx) - 1.f;
        sy = sy > 0.f ? sy : __expf(sy) - 1.f;
        ((float2*)out)[(size_t)i * 64 + lane] = make_float2(sx, sy);
        return;
    }

    // exp in-place over the wave's list + sum (same pattern as validated kernels)
    float lsum = 0.f;
    for (unsigned n = lane; n < deg; n += 64) {
        float p = __expf(pe[w][n] - lmax);
        pe[w][n] = p;
        lsum += p;
    }
    for (int o = 32; o; o >>= 1) lsum += __shfl_xor(lsum, o, 64);
    float inv = 1.0f / lsum;

    // gather: whole wave reads one 256B bf16 row per neighbor, fp32 accumulate
    float ax = 0.f, ay = 0.f;
#pragma unroll 8
    for (unsigned n = 0; n < deg; ++n) {
        float p = pe[w][n];              // LDS broadcast
        unsigned j = jl[w][n];
        ushort2 u = WhB2[(size_t)j * 64 + lane];
        ax = fmaf(p, bf2f(u.x), ax);
        ay = fmaf(p, bf2f(u.y), ay);
    }
    ax *= inv; ay *= inv;
    ax = ax > 0.f ? ax : __expf(ax) - 1.f;
    ay = ay > 0.f ? ay : __expf(ay) - 1.f;
    ((float2*)out)[(size_t)i * 64 + lane] = make_float2(ax, ay);
}

extern "C" void kernel_launch(void* const* d_in, const int* in_sizes, int n_in,
                              void* d_out, int out_size, void* d_ws, size_t ws_size,
                              hipStream_t stream) {
    const int*   edge = (const int*)d_in[0];    // [2, E] int32
    const float* X    = (const float*)d_in[1];  // [N, F]
    const float* Ws   = (const float*)d_in[2];  // [F, D]
    const float* a    = (const float*)d_in[3];  // [2D, 1]
    float*       out  = (float*)d_out;          // [N, D]
    int E = in_sizes[0] / 2;

    char* ws = (char*)d_ws;
    size_t off = 0;
    unsigned*       bm   = (unsigned*)(ws + off); off += (size_t)N_NODES * WPR * 4;   // 8 MB
    float*          s1   = (float*)(ws + off);    off += N_NODES * 4;                 // 32 KB
    float*          s2   = (float*)(ws + off);    off += N_NODES * 4;                 // 32 KB
    unsigned short* WhB  = (unsigned short*)(ws + off); off += (size_t)N_NODES * DDIM * 2; // 2 MB
    unsigned short* Bphi = (unsigned short*)(ws + off); off += (size_t)FDIM * DDIM * 2;    // 64 KB
    unsigned short* Bplo = (unsigned short*)(ws + off); off += (size_t)FDIM * DDIM * 2;    // 64 KB

    int nbuild = (E + 255) / 256;
    prep_k<<<256, 256, 0, stream>>>(Ws, Bphi, Bplo, bm);
    mega_k<<<512 + nbuild, 256, 0, stream>>>(edge, E, X, Bphi, Bplo, a, WhB, s1, s2, bm);
    row_bm_k<<<N_NODES / 4, 256, 0, stream>>>(bm, s1, s2, WhB, out);
}

// Round 18
// 40.036 us; speedup vs baseline: 4.2276x; 1.0117x over previous
//
#include <hip/hip_runtime.h>
#include <math.h>

#define N_NODES 8192
#define FDIM 256
#define DDIM 128
#define SLOPE 0.2f
#define MAXD 128        // slots/row (deduped); true max uniq deg ~50, validated R5-R17
#define NBKT 256        // buckets (32 rows each)
#define BKTCAP 2048     // packed edges per bucket region (mean 1024, +32 sigma)

typedef __attribute__((ext_vector_type(8))) short bf16x8;
typedef __attribute__((ext_vector_type(4))) float f32x4;

__device__ __forceinline__ unsigned short f2bf(float f) {     // RNE fp32->bf16
    unsigned u = __float_as_uint(f);
    u += 0x7fffu + ((u >> 16) & 1u);
    return (unsigned short)(u >> 16);
}
__device__ __forceinline__ float bf2f(unsigned short h) {
    return __uint_as_float(((unsigned)h) << 16);
}

// ---------------- k1: per-block row-bucket histogram + B-fragment pack --------------
// 1024 blocks x 256 edges. LDS hist (256 ctrs) -> coalesced u16 store. No global
// atomics anywhere in this pipeline (R15/R17 showed 262144 device-scope RMWs = ~18us
// throughput wall regardless of flavor).
__global__ __launch_bounds__(256) void prep_hist(const float* __restrict__ Ws,
                                                 const int* __restrict__ edge, int E,
                                                 unsigned short* __restrict__ Bphi,
                                                 unsigned short* __restrict__ Bplo,
                                                 unsigned short* __restrict__ counts) {
    __shared__ unsigned hcnt[NBKT];
    int bid = blockIdx.x, t = threadIdx.x;
    hcnt[t] = 0u;
    __syncthreads();
    int e = bid * 256 + t;
    if (e < E) {
        int r = edge[e];
        atomicAdd(&hcnt[r >> 5], 1u);   // LDS atomic: cheap
    }
    __syncthreads();
    counts[(size_t)bid * NBKT + t] = (unsigned short)hcnt[t];

    if (bid >= 16) return;
    // B pack (validated R16/R17): frag (ct,ks): lane l elem e = Ws[ks*32+(l>>4)*8+e][ct*16+(l&15)]
    int tid = bid * 256 + t;            // < 4096
    int ct = tid >> 9, ks = (tid >> 6) & 7, l = tid & 63;
    int kbase = ks * 32 + (l >> 4) * 8;
    int col = ct * 16 + (l & 15);
    bf16x8 h, lo;
#pragma unroll
    for (int q = 0; q < 8; q++) {
        float v = Ws[(size_t)(kbase + q) * DDIM + col];
        unsigned short hq = f2bf(v);
        h[q] = (short)hq;
        lo[q] = (short)f2bf(v - bf2f(hq));
    }
    *(bf16x8*)(Bphi + (size_t)tid * 8) = h;
    *(bf16x8*)(Bplo + (size_t)tid * 8) = lo;
}

// ---------------- k2: MFMA gemm (bid<512) || per-bucket exclusive scan (bid>=512) ---
__global__ __launch_bounds__(256) void mega2(const float* __restrict__ X,
                                             const unsigned short* __restrict__ Bphi,
                                             const unsigned short* __restrict__ Bplo,
                                             const float* __restrict__ a,
                                             unsigned short* __restrict__ WhB,
                                             float* __restrict__ s1,
                                             float* __restrict__ s2,
                                             const unsigned short* __restrict__ counts,
                                             unsigned short* __restrict__ offs,
                                             unsigned* __restrict__ btot, int nh) {
    __shared__ unsigned short Ah[16 * 264], Al[16 * 264];   // 16.5 KB (scan aliases Ah)
    __shared__ float ps1[64], ps2[64];
    __shared__ unsigned wsum[4];
    int bid = blockIdx.x, t = threadIdx.x;

    if (bid >= 512) {                   // ---- scan role: 256 blocks, one bucket each --
        int bucket = bid - 512;
        unsigned* scnt = (unsigned*)Ah;             // 1024 u32 in aliased LDS
        for (int i = t; i < 1024; i += 256)
            scnt[i] = (i < nh) ? (unsigned)counts[(size_t)i * NBKT + bucket] : 0u;
        __syncthreads();
        unsigned v0 = scnt[4 * t], v1 = scnt[4 * t + 1];
        unsigned v2 = scnt[4 * t + 2], v3 = scnt[4 * t + 3];
        unsigned lsum = v0 + v1 + v2 + v3;
        int lane = t & 63;
        unsigned x = lsum;
        for (int o = 1; o < 64; o <<= 1) {          // inclusive wave scan
            unsigned y = __shfl(x, lane - o, 64);
            if (lane >= o) x += y;
        }
        if (lane == 63) wsum[t >> 6] = x;
        __syncthreads();
        unsigned wbase = 0;
        for (int ww = 0; ww < (t >> 6); ww++) wbase += wsum[ww];
        unsigned excl = wbase + x - lsum;
        unsigned o0 = excl, o1 = o0 + v0, o2 = o1 + v1, o3 = o2 + v2;
        if (4 * t + 0 < nh) offs[(size_t)(4 * t + 0) * NBKT + bucket] = (unsigned short)o0;
        if (4 * t + 1 < nh) offs[(size_t)(4 * t + 1) * NBKT + bucket] = (unsigned short)o1;
        if (4 * t + 2 < nh) offs[(size_t)(4 * t + 2) * NBKT + bucket] = (unsigned short)o2;
        if (4 * t + 3 < nh) offs[(size_t)(4 * t + 3) * NBKT + bucket] = (unsigned short)o3;
        if (t == 255) btot[bucket] = o3 + v3;
        return;
    }

    // ---- gemm role: 512 blocks (R16/R17 validated, 7.4us measured) ----
    int w = t >> 6, lane = t & 63, lr = lane & 15, kg = lane >> 4;
    int row0 = bid * 16;

    const float4* Xg = (const float4*)(X + (size_t)row0 * FDIM);
#pragma unroll
    for (int i = 0; i < 4; i++) {
        int lin = t + 256 * i;
        int r = lin >> 6, q = lin & 63;
        float4 v = Xg[r * 64 + q];
        ushort4 h, l;
        h.x = f2bf(v.x); l.x = f2bf(v.x - bf2f(h.x));
        h.y = f2bf(v.y); l.y = f2bf(v.y - bf2f(h.y));
        h.z = f2bf(v.z); l.z = f2bf(v.z - bf2f(h.z));
        h.w = f2bf(v.w); l.w = f2bf(v.w - bf2f(h.w));
        *(ushort4*)(Ah + r * 264 + q * 4) = h;
        *(ushort4*)(Al + r * 264 + q * 4) = l;
    }
    __syncthreads();

    f32x4 acc0 = (f32x4){0.f, 0.f, 0.f, 0.f};
    f32x4 acc1 = (f32x4){0.f, 0.f, 0.f, 0.f};
    int ct0 = 2 * w, ct1 = 2 * w + 1;

#pragma unroll 2
    for (int ks = 0; ks < 8; ks++) {
        bf16x8 ahi = *(bf16x8*)(Ah + lr * 264 + ks * 32 + kg * 8);
        bf16x8 alo = *(bf16x8*)(Al + lr * 264 + ks * 32 + kg * 8);
        size_t o0 = (size_t)((ct0 * 8 + ks) * 64 + lane) * 8;
        size_t o1 = (size_t)((ct1 * 8 + ks) * 64 + lane) * 8;
        bf16x8 bh0 = *(const bf16x8*)(Bphi + o0);
        bf16x8 bl0 = *(const bf16x8*)(Bplo + o0);
        bf16x8 bh1 = *(const bf16x8*)(Bphi + o1);
        bf16x8 bl1 = *(const bf16x8*)(Bplo + o1);
        acc0 = __builtin_amdgcn_mfma_f32_16x16x32_bf16(ahi, bh0, acc0, 0, 0, 0);
        acc0 = __builtin_amdgcn_mfma_f32_16x16x32_bf16(ahi, bl0, acc0, 0, 0, 0);
        acc0 = __builtin_amdgcn_mfma_f32_16x16x32_bf16(alo, bh0, acc0, 0, 0, 0);
        acc1 = __builtin_amdgcn_mfma_f32_16x16x32_bf16(ahi, bh1, acc1, 0, 0, 0);
        acc1 = __builtin_amdgcn_mfma_f32_16x16x32_bf16(ahi, bl1, acc1, 0, 0, 0);
        acc1 = __builtin_amdgcn_mfma_f32_16x16x32_bf16(alo, bh1, acc1, 0, 0, 0);
    }

#pragma unroll
    for (int r = 0; r < 4; r++) {
        int row = row0 + kg * 4 + r;            // D: row=(lane>>4)*4+reg [m89-verified]
        int c0 = ct0 * 16 + lr, c1 = ct1 * 16 + lr;
        float v0 = acc0[r], v1 = acc1[r];
        WhB[(size_t)row * DDIM + c0] = f2bf(v0);
        WhB[(size_t)row * DDIM + c1] = f2bf(v1);
        float q1 = v0 * a[c0] + v1 * a[c1];
        float q2 = v0 * a[DDIM + c0] + v1 * a[DDIM + c1];
        for (int o = 1; o < 16; o <<= 1) {
            q1 += __shfl_xor(q1, o, 16);
            q2 += __shfl_xor(q2, o, 16);
        }
        if (lr == 0) { ps1[w * 16 + kg * 4 + r] = q1; ps2[w * 16 + kg * 4 + r] = q2; }
    }
    __syncthreads();
    if (t < 16) {
        s1[row0 + t] = (ps1[t] + ps1[16 + t]) + (ps1[32 + t] + ps1[48 + t]);
        s2[row0 + t] = (ps2[t] + ps2[16 + t]) + (ps2[32 + t] + ps2[48 + t]);
    }
}

// ---------------- k3: scatter edges into bucket regions (plain stores) --------------
__global__ __launch_bounds__(256) void scatter_k(const int* __restrict__ edge, int E,
                                                 const unsigned short* __restrict__ offs,
                                                 unsigned* __restrict__ packed) {
    __shared__ unsigned rcnt[NBKT];
    int bid = blockIdx.x, t = threadIdx.x;
    rcnt[t] = 0u;
    __syncthreads();
    int e = bid * 256 + t;
    if (e < E) {
        int r = edge[e], c = edge[E + e];
        int bucket = r >> 5;
        unsigned rank = atomicAdd(&rcnt[bucket], 1u);       // LDS atomic
        unsigned off = (unsigned)offs[(size_t)bid * NBKT + bucket] + rank;
        if (off < BKTCAP)
            packed[(size_t)bucket * BKTCAP + off] = ((unsigned)(r & 31) << 13) | (unsigned)c;
    }
}

// ---------------- k4: per-bucket dedup + compact per-row lists (LDS only) -----------
__global__ __launch_bounds__(256) void listbuild_k(const unsigned* __restrict__ packed,
                                                   const unsigned* __restrict__ btot,
                                                   unsigned* __restrict__ cntG,
                                                   unsigned* __restrict__ jlG) {
    __shared__ unsigned bmw[32 * 256];   // 32 rows x 8192-bit dedup bitmap (32 KB)
    __shared__ unsigned jls[32 * MAXD];  // 16 KB
    __shared__ unsigned lcnt[32];
    int b = blockIdx.x, t = threadIdx.x;
    for (int i = t; i < 32 * 256; i += 256) bmw[i] = 0u;
    for (int i = t; i < 32 * MAXD; i += 256) jls[i] = 0u;
    if (t < 32) lcnt[t] = 0u;
    __syncthreads();
    unsigned n = btot[b];
    if (n > BKTCAP) n = BKTCAP;
    for (unsigned idx = t; idx < n; idx += 256) {
        unsigned p = packed[(size_t)b * BKTCAP + idx];
        unsigned rl = p >> 13, c = p & 8191u;
        unsigned m = 1u << (c & 31);
        unsigned old = atomicOr(&bmw[rl * 256 + (c >> 5)], m);
        if (!(old & m)) {
            unsigned slot = atomicAdd(&lcnt[rl], 1u);
            if (slot < MAXD) jls[rl * MAXD + slot] = c;
        }
    }
    __syncthreads();
    if (t < 32) cntG[b * 32 + t] = lcnt[t];
    for (int i = t; i < 32 * MAXD; i += 256) jlG[(size_t)b * 32 * MAXD + i] = jls[i];
}

// ---------------- k5: wave-per-row softmax + bf16 gather + elu (lists pre-deduped) --
__global__ __launch_bounds__(256) void row_final(const unsigned* __restrict__ cntG,
                                                 const unsigned* __restrict__ jlG,
                                                 const float* __restrict__ s1v,
                                                 const float* __restrict__ s2v,
                                                 const unsigned short* __restrict__ WhB,
                                                 float* __restrict__ out) {
    __shared__ float    pl[4][MAXD];
    __shared__ unsigned jlw[4][MAXD];
    int w = threadIdx.x >> 6, lane = threadIdx.x & 63;
    int i = blockIdx.x * 4 + w;
    const ushort2* WhB2 = (const ushort2*)WhB;

    unsigned deg = cntG[i];
    if (deg > MAXD) deg = MAXD;

    if (deg == 0u) {
        // all-masked row -> uniform softmax -> elu(mean(Wh)); never taken on this input
        float sx = 0.f, sy = 0.f;
        for (int rr = 0; rr < N_NODES; rr++) {
            ushort2 u = WhB2[(size_t)rr * 64 + lane];
            sx += bf2f(u.x); sy += bf2f(u.y);
        }
        sx *= (1.0f / N_NODES); sy *= (1.0f / N_NODES);
        sx = sx > 0.f ? sx : __expf(sx) - 1.f;
        sy = sy > 0.f ? sy : __expf(sy) - 1.f;
        ((float2*)out)[(size_t)i * 64 + lane] = make_float2(sx, sy);
        return;
    }

    float s1 = s1v[i];
    unsigned j0 = 0u, j1 = 0u;
    float e0 = -3e38f, e1 = -3e38f;
    if (lane < (int)deg) {
        j0 = jlG[(size_t)i * MAXD + lane];
        float e = s1 + s2v[j0];
        e0 = e > 0.f ? e : SLOPE * e;
    }
    if (lane + 64 < (int)deg) {
        j1 = jlG[(size_t)i * MAXD + lane + 64];
        float e = s1 + s2v[j1];
        e1 = e > 0.f ? e : SLOPE * e;
    }

    float mx = fmaxf(e0, e1);
    for (int o = 32; o; o >>= 1) mx = fmaxf(mx, __shfl_xor(mx, o, 64));

    float p0 = (lane < (int)deg) ? __expf(e0 - mx) : 0.f;
    float p1 = (lane + 64 < (int)deg) ? __expf(e1 - mx) : 0.f;
    float s = p0 + p1;
    for (int o = 32; o; o >>= 1) s += __shfl_xor(s, o, 64);
    float inv = 1.0f / s;

    pl[w][lane] = p0;      jlw[w][lane] = j0;       // wave-private LDS, DS in-order
    pl[w][lane + 64] = p1; jlw[w][lane + 64] = j1;

    float ax = 0.f, ay = 0.f;
#pragma unroll 8
    for (unsigned n = 0; n < deg; ++n) {
        float p = pl[w][n];              // LDS broadcast
        unsigned j = jlw[w][n];
        ushort2 u = WhB2[(size_t)j * 64 + lane];
        ax = fmaf(p, bf2f(u.x), ax);
        ay = fmaf(p, bf2f(u.y), ay);
    }
    ax *= inv; ay *= inv;
    ax = ax > 0.f ? ax : __expf(ax) - 1.f;
    ay = ay > 0.f ? ay : __expf(ay) - 1.f;
    ((float2*)out)[(size_t)i * 64 + lane] = make_float2(ax, ay);
}

extern "C" void kernel_launch(void* const* d_in, const int* in_sizes, int n_in,
                              void* d_out, int out_size, void* d_ws, size_t ws_size,
                              hipStream_t stream) {
    const int*   edge = (const int*)d_in[0];    // [2, E] int32
    const float* X    = (const float*)d_in[1];  // [N, F]
    const float* Ws   = (const float*)d_in[2];  // [F, D]
    const float* a    = (const float*)d_in[3];  // [2D, 1]
    float*       out  = (float*)d_out;          // [N, D]
    int E = in_sizes[0] / 2;
    int nh = (E + 255) / 256;                   // 1024 histogram blocks

    char* ws = (char*)d_ws;
    size_t off = 0;
    unsigned short* counts = (unsigned short*)(ws + off); off += (size_t)nh * NBKT * 2;      // 512 KB
    unsigned short* offsB  = (unsigned short*)(ws + off); off += (size_t)nh * NBKT * 2;      // 512 KB
    unsigned*       btot   = (unsigned*)(ws + off);       off += 4096;                       // 1 KB pad
    unsigned*       packed = (unsigned*)(ws + off);       off += (size_t)NBKT * BKTCAP * 4;  // 2 MB
    unsigned*       cntG   = (unsigned*)(ws + off);       off += N_NODES * 4;                // 32 KB
    unsigned*       jlG    = (unsigned*)(ws + off);       off += (size_t)N_NODES * MAXD * 4; // 4 MB
    float*          s1     = (float*)(ws + off);          off += N_NODES * 4;                // 32 KB
    float*          s2     = (float*)(ws + off);          off += N_NODES * 4;                // 32 KB
    unsigned short* WhB    = (unsigned short*)(ws + off); off += (size_t)N_NODES * DDIM * 2; // 2 MB
    unsigned short* Bphi   = (unsigned short*)(ws + off); off += (size_t)FDIM * DDIM * 2;    // 64 KB
    unsigned short* Bplo   = (unsigned short*)(ws + off); off += (size_t)FDIM * DDIM * 2;    // 64 KB

    prep_hist<<<(nh > 16 ? nh : 16), 256, 0, stream>>>(Ws, edge, E, Bphi, Bplo, counts);
    mega2<<<768, 256, 0, stream>>>(X, Bphi, Bplo, a, WhB, s1, s2, counts, offsB, btot, nh);
    scatter_k<<<nh, 256, 0, stream>>>(edge, E, offsB, packed);
    listbuild_k<<<NBKT, 256, 0, stream>>>(packed, btot, cntG, jlG);
    row_final<<<N_NODES / 4, 256, 0, stream>>>(cntG, jlG, s1, s2, WhB, out);
}